// Round 2
// baseline (1096.806 us; speedup 1.0000x reference)
//
#include <hip/hip_runtime.h>
#include <hip/hip_fp16.h>
#include <hip/hip_cooperative_groups.h>

// ---------------- types & helpers ----------------
typedef _Float16 half8   __attribute__((ext_vector_type(8)));
typedef _Float16 half4v  __attribute__((ext_vector_type(4)));
typedef float    floatx4 __attribute__((ext_vector_type(4)));

#define AS1C(p) ((const __attribute__((address_space(1))) void*)(p))
#define AS3(p)  ((__attribute__((address_space(3))) void*)(p))

__device__ __forceinline__ unsigned short f2bf(float f) {
  unsigned int x = __float_as_uint(f);
  return (unsigned short)((x + 0x7fffu + ((x >> 16) & 1u)) >> 16);
}

// ---------------- problem sizes ----------------
constexpr int Bn = 1024, Cn = 10, En = 64, Xn = 768, ECn = 640;

// ---------------- ws layout (byte offsets) ----------------
constexpr size_t O_XH    = 0;          // half [2][1024*768]
constexpr size_t O_WT    = 3145728;    // half per-mlp {W0t,W1t,W2t,Wot}
constexpr size_t O_H1    = 17301504;   // half [2][1024*1024]
constexpr size_t O_H2    = 21495808;   // half [2][1024*1024]
constexpr size_t O_Q     = 25690112;   // float [2][1024*640]
constexpr size_t O_AFF   = 0;          // half [10][1024][1024]  (overlays dead region1)
constexpr size_t O_ABF   = 20971520;   // bf16 [10][1024][1024]
constexpr size_t O_QH    = 41943040;   // half [2][10][1024][64]
constexpr size_t O_BMAX  = 44564480;   // float [10][256]
constexpr size_t O_COLPA = 44574720;   // float [10][32][1024]
constexpr size_t O_COLPB = 45885440;   // float [10][32][1024]
constexpr size_t O_U     = 47196160;   // float [10][1024]

// ---------------- fp32 -> fp16 convert (x1,x2) ----------------
__global__ __launch_bounds__(256) void k_cvt_x(const float* __restrict__ x1,
                                               const float* __restrict__ x2,
                                               _Float16* __restrict__ xh) {
  int z = blockIdx.z;
  const float* s = z ? x2 : x1;
  _Float16* d = xh + (size_t)z * (Bn * Xn);
  int i = (blockIdx.x * 256 + threadIdx.x) * 4;
  float4 v = *(const float4*)(s + i);
  half4v h = { (_Float16)v.x, (_Float16)v.y, (_Float16)v.z, (_Float16)v.w };
  *(half4v*)(d + i) = h;
}

// ---------------- transpose-convert weights: src[K][N] f32 -> dst[N][K] f16 ----------------
struct TW  { const float* src; _Float16* dst; int K, N, tbase; };
struct TW8 { TW w[8]; };

__global__ __launch_bounds__(256) void k_twt(TW8 P) {
  int bid = blockIdx.x, wi = 0;
#pragma unroll
  for (int i = 1; i < 8; i++) if (bid >= P.w[i].tbase) wi = i;
  const float* src = P.w[wi].src;
  _Float16* dst = P.w[wi].dst;
  int K = P.w[wi].K, N = P.w[wi].N;
  int tid = bid - P.w[wi].tbase;
  int tN = N >> 6;
  int tk = tid / tN, tn = tid % tN;
  __shared__ float lt[64][65];
  int t = threadIdx.x;
#pragma unroll
  for (int p = 0; p < 4; p++) {
    int idx = p * 1024 + t * 4;
    int r = idx >> 6, c0 = idx & 63;
    float4 v = *(const float4*)(src + (size_t)(tk * 64 + r) * N + tn * 64 + c0);
    lt[r][c0] = v.x; lt[r][c0 + 1] = v.y; lt[r][c0 + 2] = v.z; lt[r][c0 + 3] = v.w;
  }
  __syncthreads();
#pragma unroll
  for (int p = 0; p < 4; p++) {
    int idx = p * 1024 + t * 4;
    int rn = idx >> 6, ck0 = idx & 63;
    half4v h = { (_Float16)lt[ck0][rn], (_Float16)lt[ck0 + 1][rn],
                 (_Float16)lt[ck0 + 2][rn], (_Float16)lt[ck0 + 3][rn] };
    *(half4v*)(dst + (size_t)(tn * 64 + rn) * K + tk * 64 + ck0) = h;
  }
}

// ---------------- fp16 MFMA GEMM, 2-phase double-buffered ----------------
template<int RELU, int F32OUT>
__global__ __launch_bounds__(256) void k_gemm(
    const _Float16* __restrict__ Aa, const _Float16* __restrict__ Ab,
    const _Float16* __restrict__ Ba, const _Float16* __restrict__ Bb,
    const float* __restrict__ ba, const float* __restrict__ bb,
    void* __restrict__ oa, void* __restrict__ ob, int Kd, int Nd) {
  int z = blockIdx.z;
  const _Float16* A  = z ? Ab : Aa;
  const _Float16* Bt = z ? Bb : Ba;
  const float* bias  = z ? bb : ba;
  void* outp         = z ? ob : oa;
  int m0 = blockIdx.y * 64, n0 = blockIdx.x * 64;
  int t = threadIdx.x, w = t >> 6, l = t & 63;
  int qm = w >> 1, qn = w & 1;
  __shared__ __align__(16) _Float16 lA[2][64 * 64], lB[2][64 * 64];
  floatx4 acc[2][2] = {};
  int nt = Kd >> 6;

  auto stage = [&](int p, int kt) {
#pragma unroll
    for (int q = 0; q < 2; q++) {
      int rin = 8 * q + (l >> 3);
      int sg  = (l & 7) ^ (l >> 3);
      const _Float16* gA = A  + (size_t)(m0 + 16 * w + rin) * Kd + kt + sg * 8;
      const _Float16* gB = Bt + (size_t)(n0 + 16 * w + rin) * Kd + kt + sg * 8;
      __builtin_amdgcn_global_load_lds(AS1C(gA), AS3(&lA[p][w * 1024 + q * 512]), 16, 0, 0);
      __builtin_amdgcn_global_load_lds(AS1C(gB), AS3(&lB[p][w * 1024 + q * 512]), 16, 0, 0);
    }
  };

  stage(0, 0);
  asm volatile("s_waitcnt vmcnt(0)" ::: "memory");
  __syncthreads();

  for (int ts = 0; ts < nt; ++ts) {
    int p = ts & 1;
    if (ts + 1 < nt) stage(p ^ 1, (ts + 1) * 64);   // prefetch flies under MFMA
#pragma unroll
    for (int j = 0; j < 2; j++) {
      half8 af[2], bf[2];
#pragma unroll
      for (int i = 0; i < 2; i++) {
        int ra = qm * 32 + i * 16 + (l & 15);
        int sl = 4 * j + (l >> 4);
        af[i] = *(const half8*)((const char*)lA[p] + ra * 128 + (((sl ^ (ra & 7)) & 7) << 4));
        int rb = qn * 32 + i * 16 + (l & 15);
        bf[i] = *(const half8*)((const char*)lB[p] + rb * 128 + (((sl ^ (rb & 7)) & 7) << 4));
      }
#pragma unroll
      for (int i = 0; i < 2; i++)
#pragma unroll
        for (int jj = 0; jj < 2; jj++)
          acc[i][jj] = __builtin_amdgcn_mfma_f32_16x16x32_f16(af[i], bf[jj], acc[i][jj], 0, 0, 0);
    }
    if (ts + 1 < nt) {
      asm volatile("s_waitcnt vmcnt(0)" ::: "memory");
      __syncthreads();
    }
  }
#pragma unroll
  for (int jj = 0; jj < 2; jj++) {
    int col = n0 + qn * 32 + jj * 16 + (l & 15);
    float bv = bias[col];
#pragma unroll
    for (int i = 0; i < 2; i++) {
#pragma unroll
      for (int tt = 0; tt < 4; tt++) {
        int row = m0 + qm * 32 + i * 16 + (l >> 4) * 4 + tt;
        float v = acc[i][jj][tt] + bv;
        if (RELU) v = fmaxf(v, 0.f);
        if (F32OUT) ((float*)outp)[(size_t)row * Nd + col] = v;
        else        ((_Float16*)outp)[(size_t)row * Nd + col] = (_Float16)v;
      }
    }
  }
}

// ---------------- z-score over E=64 (ddof=1) ----------------
__global__ __launch_bounds__(256) void k_zscore(const float* __restrict__ qf,
                                                _Float16* __restrict__ qh) {
  int z = blockIdx.z;
  int w = threadIdx.x >> 6, l = threadIdx.x & 63;
  int chunk = blockIdx.x * 4 + w;
  int b = chunk / Cn, c = chunk % Cn;
  float x = qf[((size_t)z * Bn + b) * ECn + c * En + l];
  float s = x, s2 = x * x;
#pragma unroll
  for (int off = 1; off < 64; off <<= 1) { s += __shfl_xor(s, off); s2 += __shfl_xor(s2, off); }
  float mu = s * (1.f / 64.f);
  float var = (s2 - 64.f * mu * mu) * (1.f / 63.f);
  float zv = (x - mu) * rsqrtf(var + 1e-8f);
  qh[(((size_t)z * Cn + c) * Bn + b) * En + l] = (_Float16)zv;
}

// ---------------- per-label affinity GEMM (K=64) + block maxes ----------------
__global__ __launch_bounds__(256) void k_aff(const _Float16* __restrict__ qh,
                                             _Float16* __restrict__ aff,
                                             float* __restrict__ bmax) {
  int c = blockIdx.z, b0 = blockIdx.y * 64, d0 = blockIdx.x * 64;
  int t = threadIdx.x, w = t >> 6, l = t & 63;
  int qm = w >> 1, qn = w & 1;
  __shared__ __align__(16) _Float16 l1[64 * 64], l2[64 * 64];
  const _Float16* q1 = qh + ((size_t)c << 16);
  const _Float16* q2 = qh + ((size_t)(Cn + c) << 16);
#pragma unroll
  for (int q = 0; q < 2; q++) {
    int rin = 8 * q + (l >> 3);
    int sg  = (l & 7) ^ (l >> 3);
    const _Float16* g1 = q1 + ((size_t)(b0 + 16 * w + rin) << 6) + sg * 8;
    const _Float16* g2 = q2 + ((size_t)(d0 + 16 * w + rin) << 6) + sg * 8;
    __builtin_amdgcn_global_load_lds(AS1C(g1), AS3(l1 + w * 1024 + q * 512), 16, 0, 0);
    __builtin_amdgcn_global_load_lds(AS1C(g2), AS3(l2 + w * 1024 + q * 512), 16, 0, 0);
  }
  asm volatile("s_waitcnt vmcnt(0)" ::: "memory");
  __syncthreads();
  floatx4 acc[2][2] = {};
#pragma unroll
  for (int j = 0; j < 2; j++) {
    half8 af[2], bf[2];
#pragma unroll
    for (int i = 0; i < 2; i++) {
      int ra = qm * 32 + i * 16 + (l & 15);
      int sl = 4 * j + (l >> 4);
      af[i] = *(const half8*)((const char*)l1 + ra * 128 + (((sl ^ (ra & 7)) & 7) << 4));
      int rb = qn * 32 + i * 16 + (l & 15);
      bf[i] = *(const half8*)((const char*)l2 + rb * 128 + (((sl ^ (rb & 7)) & 7) << 4));
    }
#pragma unroll
    for (int i = 0; i < 2; i++)
#pragma unroll
      for (int jj = 0; jj < 2; jj++)
        acc[i][jj] = __builtin_amdgcn_mfma_f32_16x16x32_f16(af[i], bf[jj], acc[i][jj], 0, 0, 0);
  }
  float mx = -1e30f;
#pragma unroll
  for (int i = 0; i < 2; i++)
#pragma unroll
    for (int jj = 0; jj < 2; jj++) {
      int col = d0 + qn * 32 + jj * 16 + (l & 15);
#pragma unroll
      for (int tt = 0; tt < 4; tt++) {
        int row = b0 + qm * 32 + i * 16 + (l >> 4) * 4 + tt;
        float v = acc[i][jj][tt] * 0.125f;
        mx = fmaxf(mx, v);
        aff[((size_t)c << 20) + ((size_t)row << 10) + col] = (_Float16)v;
      }
    }
#pragma unroll
  for (int off = 1; off < 64; off <<= 1) mx = fmaxf(mx, __shfl_xor(mx, off));
  __shared__ float sm[4];
  if (l == 0) sm[w] = mx;
  __syncthreads();
  if (t == 0)
    bmax[c * 256 + blockIdx.y * 16 + blockIdx.x] =
        fmaxf(fmaxf(sm[0], sm[1]), fmaxf(sm[2], sm[3]));
}

// ---------------- exp pass: A fp32 [b][d][c] (vectorized), bf16 planes ----------------
__global__ __launch_bounds__(256) void k_pass2(const _Float16* __restrict__ aff,
                                               const float* __restrict__ bmax,
                                               float* __restrict__ Aout,
                                               unsigned short* __restrict__ abf) {
  int b0 = blockIdx.y * 32, d0 = blockIdx.x * 32;
  int t = threadIdx.x, w = t >> 6, l = t & 63;
  __shared__ float lt[10][32][33];
  __shared__ float lmax[12];
#pragma unroll
  for (int pass = 0; pass < 3; pass++) {
    int c = pass * 4 + w;
    if (c < 10) {
      float m = -1e30f;
#pragma unroll
      for (int k = 0; k < 4; k++) m = fmaxf(m, bmax[c * 256 + k * 64 + l]);
#pragma unroll
      for (int off = 1; off < 64; off <<= 1) m = fmaxf(m, __shfl_xor(m, off));
      if (l == 0) lmax[c] = m;
    }
  }
  __syncthreads();
  int r = t >> 3, dl = (t & 7) * 4;
  for (int c = 0; c < 10; c++) {
    float mc = lmax[c];
    size_t base = ((size_t)c << 20) + ((size_t)(b0 + r) << 10) + d0 + dl;
    half4v a = *(const half4v*)(aff + base);
    float e0 = expf((float)a[0] - mc), e1 = expf((float)a[1] - mc);
    float e2 = expf((float)a[2] - mc), e3 = expf((float)a[3] - mc);
    lt[c][r][dl + 0] = e0; lt[c][r][dl + 1] = e1;
    lt[c][r][dl + 2] = e2; lt[c][r][dl + 3] = e3;
    uint2 bw;
    bw.x = (unsigned int)f2bf(e0) | ((unsigned int)f2bf(e1) << 16);
    bw.y = (unsigned int)f2bf(e2) | ((unsigned int)f2bf(e3) << 16);
    *(uint2*)(abf + base) = bw;
  }
  __syncthreads();
  // coalesced float4 stores: per row the 32d x 10c region is 1280 contiguous bytes
#pragma unroll
  for (int i = 0; i < 10; i++) {
    int q = i * 256 + t;          // 0..2559 float4 slots
    int rr = q / 80, s4 = q - rr * 80;
    floatx4 o;
#pragma unroll
    for (int k = 0; k < 4; k++) {
      int j = s4 * 4 + k;         // 0..319 within row
      int dd = j / 10, cc = j - dd * 10;
      o[k] = lt[cc][rr][dd];
    }
    *(floatx4*)(Aout + ((size_t)(b0 + rr) * 1024 + d0) * 10 + s4 * 4) = o;
  }
}

// ---------------- fused Sinkhorn: 20 iterations, one cooperative kernel ----------------
// grid = 320 blocks (c = bx>>5, rblk = bx&31); block owns 32 rows of label c's A.
// One A read per iteration: row chunk held in regs for both u-matvec and col partials.
__global__ __launch_bounds__(256) void k_sink(const unsigned short* __restrict__ abf,
                                              const float* __restrict__ p1,
                                              const float* __restrict__ p2,
                                              float* __restrict__ cpA,
                                              float* __restrict__ cpB,
                                              float* __restrict__ u_buf) {
  cooperative_groups::grid_group gg = cooperative_groups::this_grid();
  int bx = blockIdx.x;
  int c = bx >> 5, rblk = bx & 31;
  int t = threadIdx.x, w = t >> 6, l = t & 63;
  __shared__ float v_lds[1024];
  __shared__ float cacc[4][1024];
  const unsigned short* Ac = abf + ((size_t)c << 20);
  for (int it = 0; it < 20; ++it) {
    float v[16];
    if (it == 0) {
#pragma unroll
      for (int j = 0; j < 16; j++) v[j] = 1.f;
    } else {
      const float* src = (it & 1) ? cpA : cpB;
      for (int d = t; d < 1024; d += 256) {
        float s = 0.f;
#pragma unroll
        for (int k = 0; k < 32; k++) s += src[((size_t)(c * 32 + k) << 10) + d];
        v_lds[d] = p2[d * 10 + c] / (s + 1e-12f);
      }
      __syncthreads();
#pragma unroll
      for (int j4 = 0; j4 < 4; j4++) {
        float4 f = *(const float4*)&v_lds[l * 16 + j4 * 4];
        v[4 * j4] = f.x; v[4 * j4 + 1] = f.y; v[4 * j4 + 2] = f.z; v[4 * j4 + 3] = f.w;
      }
    }
    float ca[16];
#pragma unroll
    for (int j = 0; j < 16; j++) ca[j] = 0.f;
#pragma unroll 2
    for (int ri = 0; ri < 8; ri++) {
      int b = rblk * 32 + w * 8 + ri;
      const unsigned short* row = Ac + ((size_t)b << 10) + l * 16;
      uint4 a0 = *(const uint4*)row;
      uint4 a1 = *(const uint4*)(row + 8);
      unsigned int pk[8] = { a0.x, a0.y, a0.z, a0.w, a1.x, a1.y, a1.z, a1.w };
      float af[16];
#pragma unroll
      for (int i = 0; i < 8; i++) {
        af[2 * i]     = __uint_as_float(pk[i] << 16);
        af[2 * i + 1] = __uint_as_float(pk[i] & 0xffff0000u);
      }
      float s0 = 0.f, s1 = 0.f, s2 = 0.f, s3 = 0.f;
#pragma unroll
      for (int j = 0; j < 4; j++) {
        s0 = fmaf(af[j],      v[j],      s0);
        s1 = fmaf(af[4 + j],  v[4 + j],  s1);
        s2 = fmaf(af[8 + j],  v[8 + j],  s2);
        s3 = fmaf(af[12 + j], v[12 + j], s3);
      }
      float s = (s0 + s1) + (s2 + s3);
#pragma unroll
      for (int off = 1; off < 64; off <<= 1) s += __shfl_xor(s, off);
      float u = p1[b * 10 + c] / (s + 1e-12f);
#pragma unroll
      for (int j = 0; j < 16; j++) ca[j] = fmaf(af[j], u, ca[j]);
      if (it == 19 && l == 0) u_buf[(c << 10) + b] = u;
    }
#pragma unroll
    for (int j = 0; j < 16; j++) cacc[w][l * 16 + j] = ca[j];
    __syncthreads();
    float* dst = (it & 1) ? cpB : cpA;
    for (int d = t; d < 1024; d += 256)
      dst[((size_t)(c * 32 + rblk) << 10) + d] =
          cacc[0][d] + cacc[1][d] + cacc[2][d] + cacc[3][d];
    gg.sync();
  }
}

// ---------------- final P = u o A o v, coalesced [b][d][c] writes ----------------
__global__ __launch_bounds__(256) void k_pwrite(const unsigned short* __restrict__ abf,
                                                const float* __restrict__ colp,
                                                const float* __restrict__ u_buf,
                                                const float* __restrict__ p2,
                                                float* __restrict__ Pout) {
  int b0 = blockIdx.y * 32, d0 = blockIdx.x * 32, t = threadIdx.x;
  __shared__ float pt[10][32][33];
  __shared__ float vl[10][32], ul[10][32];
  for (int p = t; p < 320; p += 256) {
    int c = p >> 5, j = p & 31;
    int d = d0 + j;
    float s = 0.f;
#pragma unroll
    for (int k = 0; k < 32; k++) s += colp[((size_t)(c * 32 + k) << 10) + d];
    vl[c][j] = p2[d * 10 + c] / (s + 1e-12f);
    ul[c][j] = u_buf[(c << 10) + b0 + j];
  }
  __syncthreads();
  int r = t >> 3, dl = (t & 7) * 4;
  for (int c = 0; c < 10; c++) {
    uint2 p = *(const uint2*)(abf + ((size_t)c << 20) + ((size_t)(b0 + r) << 10) + d0 + dl);
    float u = ul[c][r];
    pt[c][r][dl + 0] = u * __uint_as_float(p.x << 16)         * vl[c][dl + 0];
    pt[c][r][dl + 1] = u * __uint_as_float(p.x & 0xffff0000u) * vl[c][dl + 1];
    pt[c][r][dl + 2] = u * __uint_as_float(p.y << 16)         * vl[c][dl + 2];
    pt[c][r][dl + 3] = u * __uint_as_float(p.y & 0xffff0000u) * vl[c][dl + 3];
  }
  __syncthreads();
#pragma unroll
  for (int i = 0; i < 10; i++) {
    int q = i * 256 + t;
    int rr = q / 80, s4 = q - rr * 80;
    floatx4 o;
#pragma unroll
    for (int k = 0; k < 4; k++) {
      int j = s4 * 4 + k;
      int dd = j / 10, cc = j - dd * 10;
      o[k] = pt[cc][rr][dd];
    }
    *(floatx4*)(Pout + ((size_t)(b0 + rr) * 1024 + d0) * 10 + s4 * 4) = o;
  }
}

// ---------------- launch ----------------
extern "C" void kernel_launch(void* const* d_in, const int* in_sizes, int n_in,
                              void* d_out, int out_size, void* d_ws, size_t ws_size,
                              hipStream_t stream) {
  (void)in_sizes; (void)n_in; (void)out_size; (void)ws_size;
  char* ws = (char*)d_ws;
  const float* x1 = (const float*)d_in[0];
  const float* x2 = (const float*)d_in[1];
  const float* p1 = (const float*)d_in[2];
  const float* p2 = (const float*)d_in[3];

  _Float16* xh  = (_Float16*)(ws + O_XH);
  _Float16* wt  = (_Float16*)(ws + O_WT);
  _Float16* h1  = (_Float16*)(ws + O_H1);
  _Float16* h2  = (_Float16*)(ws + O_H2);
  float*    qf  = (float*)(ws + O_Q);
  _Float16* aff = (_Float16*)(ws + O_AFF);
  unsigned short* abf = (unsigned short*)(ws + O_ABF);
  _Float16* qh  = (_Float16*)(ws + O_QH);
  float* bmax  = (float*)(ws + O_BMAX);
  float* colpA = (float*)(ws + O_COLPA);
  float* colpB = (float*)(ws + O_COLPB);
  float* ub    = (float*)(ws + O_U);
  float* Pout = (float*)d_out;
  float* Aout = Pout + (size_t)Bn * Bn * Cn;

  k_cvt_x<<<dim3(768, 1, 2), 256, 0, stream>>>(x1, x2, xh);

  TW8 tw;
  const int    wK[4]   = { 768, 1024, 1024, 1024 };
  const int    wN[4]   = { 1024, 1024, 1024, 640 };
  const size_t wOff[4] = { 0, 786432, 1835008, 2883584 };
  const int    wTb[8]  = { 0, 192, 448, 704, 864, 1056, 1312, 1568 };
  for (int m = 0; m < 2; m++)
    for (int i = 0; i < 4; i++) {
      int idx = m * 4 + i;
      tw.w[idx].src = (const float*)d_in[4 + m * 8 + i * 2];
      tw.w[idx].dst = wt + (size_t)m * 3538944 + wOff[i];
      tw.w[idx].K = wK[i]; tw.w[idx].N = wN[i]; tw.w[idx].tbase = wTb[idx];
    }
  k_twt<<<1728, 256, 0, stream>>>(tw);

  const float* b0a = (const float*)d_in[5];  const float* b0b = (const float*)d_in[13];
  const float* b1a = (const float*)d_in[7];  const float* b1b = (const float*)d_in[15];
  const float* b2a = (const float*)d_in[9];  const float* b2b = (const float*)d_in[17];
  const float* boa = (const float*)d_in[11]; const float* bob = (const float*)d_in[19];

  k_gemm<1, 0><<<dim3(16, 16, 2), 256, 0, stream>>>(
      xh, xh + 786432, wt, wt + 3538944, b0a, b0b, h1, h1 + 1048576, 768, 1024);
  k_gemm<1, 0><<<dim3(16, 16, 2), 256, 0, stream>>>(
      h1, h1 + 1048576, wt + 786432, wt + 3538944 + 786432, b1a, b1b,
      h2, h2 + 1048576, 1024, 1024);
  k_gemm<1, 0><<<dim3(16, 16, 2), 256, 0, stream>>>(
      h2, h2 + 1048576, wt + 1835008, wt + 3538944 + 1835008, b2a, b2b,
      h1, h1 + 1048576, 1024, 1024);
  k_gemm<0, 1><<<dim3(10, 16, 2), 256, 0, stream>>>(
      h1, h1 + 1048576, wt + 2883584, wt + 3538944 + 2883584, boa, bob,
      qf, qf + 655360, 1024, 640);

  k_zscore<<<dim3(2560, 1, 2), 256, 0, stream>>>(qf, qh);
  k_aff<<<dim3(16, 16, 10), 256, 0, stream>>>(qh, aff, bmax);
  k_pass2<<<dim3(32, 32), 256, 0, stream>>>(aff, bmax, Aout, abf);

  // fused Sinkhorn (cooperative, 320 blocks <= 2 blocks/CU co-resident)
  {
    const unsigned short* abf_c = abf;
    void* args[] = { (void*)&abf_c, (void*)&p1, (void*)&p2,
                     (void*)&colpA, (void*)&colpB, (void*)&ub };
    hipLaunchCooperativeKernel((const void*)k_sink, dim3(320), dim3(256),
                               args, 0, stream);
  }

  k_pwrite<<<dim3(32, 32), 256, 0, stream>>>(abf, colpB, ub, p2, Pout);
}

// Round 3
// 377.942 us; speedup vs baseline: 2.9020x; 2.9020x over previous
//
#include <hip/hip_runtime.h>
#include <hip/hip_fp16.h>

// ---------------- types & helpers ----------------
typedef _Float16 half8   __attribute__((ext_vector_type(8)));
typedef _Float16 half4v  __attribute__((ext_vector_type(4)));
typedef float    floatx4 __attribute__((ext_vector_type(4)));

#define AS1C(p) ((const __attribute__((address_space(1))) void*)(p))
#define AS3(p)  ((__attribute__((address_space(3))) void*)(p))

__device__ __forceinline__ unsigned short f2bf(float f) {
  unsigned int x = __float_as_uint(f);
  return (unsigned short)((x + 0x7fffu + ((x >> 16) & 1u)) >> 16);
}

// ---------------- problem sizes ----------------
constexpr int Bn = 1024, Cn = 10, En = 64, Xn = 768, ECn = 640;

// ---------------- ws layout (byte offsets) ----------------
constexpr size_t O_XH    = 0;          // half [2][1024*768]
constexpr size_t O_WT    = 3145728;    // half per-mlp {W0t,W1t,W2t,Wot}
constexpr size_t O_H1    = 17301504;   // half [2][1024*1024]
constexpr size_t O_H2    = 21495808;   // half [2][1024*1024]
constexpr size_t O_Q     = 25690112;   // float [2][1024*640]
constexpr size_t O_AFF   = 0;          // half [10][1024][1024]  (overlays dead region1)
constexpr size_t O_SLOTS = 0;          // float [20][10][1024]   (overlays dead aff after pass2)
constexpr size_t O_ABF   = 20971520;   // bf16 [10][1024][1024]
constexpr size_t O_QH    = 41943040;   // half [2][10][1024][64]
constexpr size_t O_BMAX  = 44564480;   // float [10][256]
constexpr size_t O_U     = 47196160;   // float [10][1024]

// ---------------- fp32 -> fp16 convert (x1,x2) ----------------
__global__ __launch_bounds__(256) void k_cvt_x(const float* __restrict__ x1,
                                               const float* __restrict__ x2,
                                               _Float16* __restrict__ xh) {
  int z = blockIdx.z;
  const float* s = z ? x2 : x1;
  _Float16* d = xh + (size_t)z * (Bn * Xn);
  int i = (blockIdx.x * 256 + threadIdx.x) * 4;
  float4 v = *(const float4*)(s + i);
  half4v h = { (_Float16)v.x, (_Float16)v.y, (_Float16)v.z, (_Float16)v.w };
  *(half4v*)(d + i) = h;
}

// ---------------- transpose-convert weights: src[K][N] f32 -> dst[N][K] f16 ----------------
struct TW  { const float* src; _Float16* dst; int K, N, tbase; };
struct TW8 { TW w[8]; };

__global__ __launch_bounds__(256) void k_twt(TW8 P) {
  int bid = blockIdx.x, wi = 0;
#pragma unroll
  for (int i = 1; i < 8; i++) if (bid >= P.w[i].tbase) wi = i;
  const float* src = P.w[wi].src;
  _Float16* dst = P.w[wi].dst;
  int K = P.w[wi].K, N = P.w[wi].N;
  int tid = bid - P.w[wi].tbase;
  int tN = N >> 6;
  int tk = tid / tN, tn = tid % tN;
  __shared__ float lt[64][65];
  int t = threadIdx.x;
#pragma unroll
  for (int p = 0; p < 4; p++) {
    int idx = p * 1024 + t * 4;
    int r = idx >> 6, c0 = idx & 63;
    float4 v = *(const float4*)(src + (size_t)(tk * 64 + r) * N + tn * 64 + c0);
    lt[r][c0] = v.x; lt[r][c0 + 1] = v.y; lt[r][c0 + 2] = v.z; lt[r][c0 + 3] = v.w;
  }
  __syncthreads();
#pragma unroll
  for (int p = 0; p < 4; p++) {
    int idx = p * 1024 + t * 4;
    int rn = idx >> 6, ck0 = idx & 63;
    half4v h = { (_Float16)lt[ck0][rn], (_Float16)lt[ck0 + 1][rn],
                 (_Float16)lt[ck0 + 2][rn], (_Float16)lt[ck0 + 3][rn] };
    *(half4v*)(dst + (size_t)(tn * 64 + rn) * K + tk * 64 + ck0) = h;
  }
}

// ---------------- fp16 MFMA GEMM, 2-phase double-buffered ----------------
template<int RELU, int F32OUT>
__global__ __launch_bounds__(256) void k_gemm(
    const _Float16* __restrict__ Aa, const _Float16* __restrict__ Ab,
    const _Float16* __restrict__ Ba, const _Float16* __restrict__ Bb,
    const float* __restrict__ ba, const float* __restrict__ bb,
    void* __restrict__ oa, void* __restrict__ ob, int Kd, int Nd) {
  int z = blockIdx.z;
  const _Float16* A  = z ? Ab : Aa;
  const _Float16* Bt = z ? Bb : Ba;
  const float* bias  = z ? bb : ba;
  void* outp         = z ? ob : oa;
  int m0 = blockIdx.y * 64, n0 = blockIdx.x * 64;
  int t = threadIdx.x, w = t >> 6, l = t & 63;
  int qm = w >> 1, qn = w & 1;
  __shared__ __align__(16) _Float16 lA[2][64 * 64], lB[2][64 * 64];
  floatx4 acc[2][2] = {};
  int nt = Kd >> 6;

  auto stage = [&](int p, int kt) {
#pragma unroll
    for (int q = 0; q < 2; q++) {
      int rin = 8 * q + (l >> 3);
      int sg  = (l & 7) ^ (l >> 3);
      const _Float16* gA = A  + (size_t)(m0 + 16 * w + rin) * Kd + kt + sg * 8;
      const _Float16* gB = Bt + (size_t)(n0 + 16 * w + rin) * Kd + kt + sg * 8;
      __builtin_amdgcn_global_load_lds(AS1C(gA), AS3(&lA[p][w * 1024 + q * 512]), 16, 0, 0);
      __builtin_amdgcn_global_load_lds(AS1C(gB), AS3(&lB[p][w * 1024 + q * 512]), 16, 0, 0);
    }
  };

  stage(0, 0);
  asm volatile("s_waitcnt vmcnt(0)" ::: "memory");
  __syncthreads();

  for (int ts = 0; ts < nt; ++ts) {
    int p = ts & 1;
    if (ts + 1 < nt) stage(p ^ 1, (ts + 1) * 64);   // prefetch flies under MFMA
#pragma unroll
    for (int j = 0; j < 2; j++) {
      half8 af[2], bf[2];
#pragma unroll
      for (int i = 0; i < 2; i++) {
        int ra = qm * 32 + i * 16 + (l & 15);
        int sl = 4 * j + (l >> 4);
        af[i] = *(const half8*)((const char*)lA[p] + ra * 128 + (((sl ^ (ra & 7)) & 7) << 4));
        int rb = qn * 32 + i * 16 + (l & 15);
        bf[i] = *(const half8*)((const char*)lB[p] + rb * 128 + (((sl ^ (rb & 7)) & 7) << 4));
      }
#pragma unroll
      for (int i = 0; i < 2; i++)
#pragma unroll
        for (int jj = 0; jj < 2; jj++)
          acc[i][jj] = __builtin_amdgcn_mfma_f32_16x16x32_f16(af[i], bf[jj], acc[i][jj], 0, 0, 0);
    }
    if (ts + 1 < nt) {
      asm volatile("s_waitcnt vmcnt(0)" ::: "memory");
      __syncthreads();
    }
  }
#pragma unroll
  for (int jj = 0; jj < 2; jj++) {
    int col = n0 + qn * 32 + jj * 16 + (l & 15);
    float bv = bias[col];
#pragma unroll
    for (int i = 0; i < 2; i++) {
#pragma unroll
      for (int tt = 0; tt < 4; tt++) {
        int row = m0 + qm * 32 + i * 16 + (l >> 4) * 4 + tt;
        float v = acc[i][jj][tt] + bv;
        if (RELU) v = fmaxf(v, 0.f);
        if (F32OUT) ((float*)outp)[(size_t)row * Nd + col] = v;
        else        ((_Float16*)outp)[(size_t)row * Nd + col] = (_Float16)v;
      }
    }
  }
}

// ---------------- z-score over E=64 (ddof=1) ----------------
__global__ __launch_bounds__(256) void k_zscore(const float* __restrict__ qf,
                                                _Float16* __restrict__ qh) {
  int z = blockIdx.z;
  int w = threadIdx.x >> 6, l = threadIdx.x & 63;
  int chunk = blockIdx.x * 4 + w;
  int b = chunk / Cn, c = chunk % Cn;
  float x = qf[((size_t)z * Bn + b) * ECn + c * En + l];
  float s = x, s2 = x * x;
#pragma unroll
  for (int off = 1; off < 64; off <<= 1) { s += __shfl_xor(s, off); s2 += __shfl_xor(s2, off); }
  float mu = s * (1.f / 64.f);
  float var = (s2 - 64.f * mu * mu) * (1.f / 63.f);
  float zv = (x - mu) * rsqrtf(var + 1e-8f);
  qh[(((size_t)z * Cn + c) * Bn + b) * En + l] = (_Float16)zv;
}

// ---------------- per-label affinity GEMM (K=64) + block maxes ----------------
__global__ __launch_bounds__(256) void k_aff(const _Float16* __restrict__ qh,
                                             _Float16* __restrict__ aff,
                                             float* __restrict__ bmax) {
  int c = blockIdx.z, b0 = blockIdx.y * 64, d0 = blockIdx.x * 64;
  int t = threadIdx.x, w = t >> 6, l = t & 63;
  int qm = w >> 1, qn = w & 1;
  __shared__ __align__(16) _Float16 l1[64 * 64], l2[64 * 64];
  const _Float16* q1 = qh + ((size_t)c << 16);
  const _Float16* q2 = qh + ((size_t)(Cn + c) << 16);
#pragma unroll
  for (int q = 0; q < 2; q++) {
    int rin = 8 * q + (l >> 3);
    int sg  = (l & 7) ^ (l >> 3);
    const _Float16* g1 = q1 + ((size_t)(b0 + 16 * w + rin) << 6) + sg * 8;
    const _Float16* g2 = q2 + ((size_t)(d0 + 16 * w + rin) << 6) + sg * 8;
    __builtin_amdgcn_global_load_lds(AS1C(g1), AS3(l1 + w * 1024 + q * 512), 16, 0, 0);
    __builtin_amdgcn_global_load_lds(AS1C(g2), AS3(l2 + w * 1024 + q * 512), 16, 0, 0);
  }
  asm volatile("s_waitcnt vmcnt(0)" ::: "memory");
  __syncthreads();
  floatx4 acc[2][2] = {};
#pragma unroll
  for (int j = 0; j < 2; j++) {
    half8 af[2], bf[2];
#pragma unroll
    for (int i = 0; i < 2; i++) {
      int ra = qm * 32 + i * 16 + (l & 15);
      int sl = 4 * j + (l >> 4);
      af[i] = *(const half8*)((const char*)l1 + ra * 128 + (((sl ^ (ra & 7)) & 7) << 4));
      int rb = qn * 32 + i * 16 + (l & 15);
      bf[i] = *(const half8*)((const char*)l2 + rb * 128 + (((sl ^ (rb & 7)) & 7) << 4));
    }
#pragma unroll
    for (int i = 0; i < 2; i++)
#pragma unroll
      for (int jj = 0; jj < 2; jj++)
        acc[i][jj] = __builtin_amdgcn_mfma_f32_16x16x32_f16(af[i], bf[jj], acc[i][jj], 0, 0, 0);
  }
  float mx = -1e30f;
#pragma unroll
  for (int i = 0; i < 2; i++)
#pragma unroll
    for (int jj = 0; jj < 2; jj++) {
      int col = d0 + qn * 32 + jj * 16 + (l & 15);
#pragma unroll
      for (int tt = 0; tt < 4; tt++) {
        int row = b0 + qm * 32 + i * 16 + (l >> 4) * 4 + tt;
        float v = acc[i][jj][tt] * 0.125f;
        mx = fmaxf(mx, v);
        aff[((size_t)c << 20) + ((size_t)row << 10) + col] = (_Float16)v;
      }
    }
#pragma unroll
  for (int off = 1; off < 64; off <<= 1) mx = fmaxf(mx, __shfl_xor(mx, off));
  __shared__ float sm[4];
  if (l == 0) sm[w] = mx;
  __syncthreads();
  if (t == 0)
    bmax[c * 256 + blockIdx.y * 16 + blockIdx.x] =
        fmaxf(fmaxf(sm[0], sm[1]), fmaxf(sm[2], sm[3]));
}

// ---------------- exp pass: A fp32 [b][d][c] (vectorized), bf16 planes ----------------
__global__ __launch_bounds__(256) void k_pass2(const _Float16* __restrict__ aff,
                                               const float* __restrict__ bmax,
                                               float* __restrict__ Aout,
                                               unsigned short* __restrict__ abf) {
  int b0 = blockIdx.y * 32, d0 = blockIdx.x * 32;
  int t = threadIdx.x, w = t >> 6, l = t & 63;
  __shared__ float lt[10][32][33];
  __shared__ float lmax[12];
#pragma unroll
  for (int pass = 0; pass < 3; pass++) {
    int c = pass * 4 + w;
    if (c < 10) {
      float m = -1e30f;
#pragma unroll
      for (int k = 0; k < 4; k++) m = fmaxf(m, bmax[c * 256 + k * 64 + l]);
#pragma unroll
      for (int off = 1; off < 64; off <<= 1) m = fmaxf(m, __shfl_xor(m, off));
      if (l == 0) lmax[c] = m;
    }
  }
  __syncthreads();
  int r = t >> 3, dl = (t & 7) * 4;
  for (int c = 0; c < 10; c++) {
    float mc = lmax[c];
    size_t base = ((size_t)c << 20) + ((size_t)(b0 + r) << 10) + d0 + dl;
    half4v a = *(const half4v*)(aff + base);
    float e0 = expf((float)a[0] - mc), e1 = expf((float)a[1] - mc);
    float e2 = expf((float)a[2] - mc), e3 = expf((float)a[3] - mc);
    lt[c][r][dl + 0] = e0; lt[c][r][dl + 1] = e1;
    lt[c][r][dl + 2] = e2; lt[c][r][dl + 3] = e3;
    uint2 bw;
    bw.x = (unsigned int)f2bf(e0) | ((unsigned int)f2bf(e1) << 16);
    bw.y = (unsigned int)f2bf(e2) | ((unsigned int)f2bf(e3) << 16);
    *(uint2*)(abf + base) = bw;
  }
  __syncthreads();
#pragma unroll
  for (int i = 0; i < 10; i++) {
    int q = i * 256 + t;
    int rr = q / 80, s4 = q - rr * 80;
    floatx4 o;
#pragma unroll
    for (int k = 0; k < 4; k++) {
      int j = s4 * 4 + k;
      int dd = j / 10, cc = j - dd * 10;
      o[k] = lt[cc][rr][dd];
    }
    *(floatx4*)(Aout + ((size_t)(b0 + rr) * 1024 + d0) * 10 + s4 * 4) = o;
  }
}

// ---------------- zero the 20 colsum slots ----------------
__global__ __launch_bounds__(256) void k_zero(float* __restrict__ p) {
  int i = (blockIdx.x * 256 + threadIdx.x) * 4;
  floatx4 z = { 0.f, 0.f, 0.f, 0.f };
  *(floatx4*)(p + i) = z;
}

// ---------------- one Sinkhorn iteration per launch, single A pass ----------------
// grid (32,10): block = 32 rows of label c. Wave w: rows rblk*32+w*8..+7.
// Lane l covers cols {l*8..l*8+7} u {512+l*8..+7}. Row regs reused for the
// u-dot AND the column accumulation; colsums go out via global atomicAdd.
template<int FIRST>
__global__ __launch_bounds__(256) void k_it(const unsigned short* __restrict__ abf,
                                            const float* __restrict__ p1,
                                            const float* __restrict__ p2,
                                            const float* __restrict__ csrc,
                                            float* __restrict__ cdst,
                                            float* __restrict__ u_buf,
                                            int last) {
  int rblk = blockIdx.x, c = blockIdx.y;
  int t = threadIdx.x, w = t >> 6, l = t & 63;
  __shared__ float v_lds[1024];
  __shared__ float cacc[4][1024];
  const unsigned short* Ac = abf + ((size_t)c << 20);

  float v[16];
  if (FIRST) {
#pragma unroll
    for (int j = 0; j < 16; j++) v[j] = 1.f;
  } else {
    int d = t * 4;
    float4 cs = *(const float4*)(csrc + (c << 10) + d);
    float4 vv;
    vv.x = p2[(d + 0) * 10 + c] / (cs.x + 1e-12f);
    vv.y = p2[(d + 1) * 10 + c] / (cs.y + 1e-12f);
    vv.z = p2[(d + 2) * 10 + c] / (cs.z + 1e-12f);
    vv.w = p2[(d + 3) * 10 + c] / (cs.w + 1e-12f);
    *(float4*)&v_lds[d] = vv;
    __syncthreads();
    float4 va = *(const float4*)&v_lds[l * 8];
    float4 vb = *(const float4*)&v_lds[l * 8 + 4];
    float4 vc = *(const float4*)&v_lds[512 + l * 8];
    float4 vd = *(const float4*)&v_lds[512 + l * 8 + 4];
    v[0] = va.x;  v[1] = va.y;  v[2] = va.z;  v[3] = va.w;
    v[4] = vb.x;  v[5] = vb.y;  v[6] = vb.z;  v[7] = vb.w;
    v[8] = vc.x;  v[9] = vc.y;  v[10] = vc.z; v[11] = vc.w;
    v[12] = vd.x; v[13] = vd.y; v[14] = vd.z; v[15] = vd.w;
  }

  float ca[16];
#pragma unroll
  for (int j = 0; j < 16; j++) ca[j] = 0.f;

#pragma unroll 2
  for (int ri = 0; ri < 8; ri++) {
    int b = rblk * 32 + w * 8 + ri;
    const unsigned short* row = Ac + ((size_t)b << 10);
    uint4 a0 = *(const uint4*)(row + l * 8);         // cols l*8..+7
    uint4 a1 = *(const uint4*)(row + 512 + l * 8);   // cols 512+l*8..+7
    unsigned int pk[8] = { a0.x, a0.y, a0.z, a0.w, a1.x, a1.y, a1.z, a1.w };
    float af[16];
#pragma unroll
    for (int i = 0; i < 8; i++) {
      af[2 * i]     = __uint_as_float(pk[i] << 16);
      af[2 * i + 1] = __uint_as_float(pk[i] & 0xffff0000u);
    }
    float s0 = 0.f, s1 = 0.f, s2 = 0.f, s3 = 0.f;
#pragma unroll
    for (int j = 0; j < 4; j++) {
      s0 = fmaf(af[j],      v[j],      s0);
      s1 = fmaf(af[4 + j],  v[4 + j],  s1);
      s2 = fmaf(af[8 + j],  v[8 + j],  s2);
      s3 = fmaf(af[12 + j], v[12 + j], s3);
    }
    float s = (s0 + s1) + (s2 + s3);
#pragma unroll
    for (int off = 1; off < 64; off <<= 1) s += __shfl_xor(s, off);
    float u = p1[b * 10 + c] / (s + 1e-12f);
#pragma unroll
    for (int j = 0; j < 16; j++) ca[j] = fmaf(af[j], u, ca[j]);
    if (last && l == 0) u_buf[(c << 10) + b] = u;
  }

  // combine the 4 waves' column partials in LDS, then one atomicAdd per column
  *(floatx4*)&cacc[w][l * 8]           = *(floatx4*)&ca[0];
  *(floatx4*)&cacc[w][l * 8 + 4]       = *(floatx4*)&ca[4];
  *(floatx4*)&cacc[w][512 + l * 8]     = *(floatx4*)&ca[8];
  *(floatx4*)&cacc[w][512 + l * 8 + 4] = *(floatx4*)&ca[12];
  __syncthreads();
  int d0 = t * 4;
  floatx4 s0 = *(floatx4*)&cacc[0][d0];
  floatx4 s1 = *(floatx4*)&cacc[1][d0];
  floatx4 s2 = *(floatx4*)&cacc[2][d0];
  floatx4 s3 = *(floatx4*)&cacc[3][d0];
  floatx4 ss = (s0 + s1) + (s2 + s3);
#pragma unroll
  for (int k = 0; k < 4; k++) atomicAdd(&cdst[(c << 10) + d0 + k], ss[k]);
}

// ---------------- final P = u o A o v, coalesced [b][d][c] writes ----------------
__global__ __launch_bounds__(256) void k_pwrite(const unsigned short* __restrict__ abf,
                                                const float* __restrict__ csum,
                                                const float* __restrict__ u_buf,
                                                const float* __restrict__ p2,
                                                float* __restrict__ Pout) {
  int b0 = blockIdx.y * 32, d0 = blockIdx.x * 32, t = threadIdx.x;
  __shared__ float pt[10][32][33];
  __shared__ float vl[10][32], ul[10][32];
  for (int p = t; p < 320; p += 256) {
    int c = p >> 5, j = p & 31;
    int d = d0 + j;
    vl[c][j] = p2[d * 10 + c] / (csum[(c << 10) + d] + 1e-12f);
    ul[c][j] = u_buf[(c << 10) + b0 + j];
  }
  __syncthreads();
  int r = t >> 3, dl = (t & 7) * 4;
  for (int c = 0; c < 10; c++) {
    uint2 p = *(const uint2*)(abf + ((size_t)c << 20) + ((size_t)(b0 + r) << 10) + d0 + dl);
    float u = ul[c][r];
    pt[c][r][dl + 0] = u * __uint_as_float(p.x << 16)         * vl[c][dl + 0];
    pt[c][r][dl + 1] = u * __uint_as_float(p.x & 0xffff0000u) * vl[c][dl + 1];
    pt[c][r][dl + 2] = u * __uint_as_float(p.y << 16)         * vl[c][dl + 2];
    pt[c][r][dl + 3] = u * __uint_as_float(p.y & 0xffff0000u) * vl[c][dl + 3];
  }
  __syncthreads();
#pragma unroll
  for (int i = 0; i < 10; i++) {
    int q = i * 256 + t;
    int rr = q / 80, s4 = q - rr * 80;
    floatx4 o;
#pragma unroll
    for (int k = 0; k < 4; k++) {
      int j = s4 * 4 + k;
      int dd = j / 10, cc = j - dd * 10;
      o[k] = pt[cc][rr][dd];
    }
    *(floatx4*)(Pout + ((size_t)(b0 + rr) * 1024 + d0) * 10 + s4 * 4) = o;
  }
}

// ---------------- launch ----------------
extern "C" void kernel_launch(void* const* d_in, const int* in_sizes, int n_in,
                              void* d_out, int out_size, void* d_ws, size_t ws_size,
                              hipStream_t stream) {
  (void)in_sizes; (void)n_in; (void)out_size; (void)ws_size;
  char* ws = (char*)d_ws;
  const float* x1 = (const float*)d_in[0];
  const float* x2 = (const float*)d_in[1];
  const float* p1 = (const float*)d_in[2];
  const float* p2 = (const float*)d_in[3];

  _Float16* xh  = (_Float16*)(ws + O_XH);
  _Float16* wt  = (_Float16*)(ws + O_WT);
  _Float16* h1  = (_Float16*)(ws + O_H1);
  _Float16* h2  = (_Float16*)(ws + O_H2);
  float*    qf  = (float*)(ws + O_Q);
  _Float16* aff = (_Float16*)(ws + O_AFF);
  float*  slots = (float*)(ws + O_SLOTS);      // 20 x [10][1024], overlays dead aff
  unsigned short* abf = (unsigned short*)(ws + O_ABF);
  _Float16* qh  = (_Float16*)(ws + O_QH);
  float* bmax  = (float*)(ws + O_BMAX);
  float* ub    = (float*)(ws + O_U);
  float* Pout = (float*)d_out;
  float* Aout = Pout + (size_t)Bn * Bn * Cn;

  k_cvt_x<<<dim3(768, 1, 2), 256, 0, stream>>>(x1, x2, xh);

  TW8 tw;
  const int    wK[4]   = { 768, 1024, 1024, 1024 };
  const int    wN[4]   = { 1024, 1024, 1024, 640 };
  const size_t wOff[4] = { 0, 786432, 1835008, 2883584 };
  const int    wTb[8]  = { 0, 192, 448, 704, 864, 1056, 1312, 1568 };
  for (int m = 0; m < 2; m++)
    for (int i = 0; i < 4; i++) {
      int idx = m * 4 + i;
      tw.w[idx].src = (const float*)d_in[4 + m * 8 + i * 2];
      tw.w[idx].dst = wt + (size_t)m * 3538944 + wOff[i];
      tw.w[idx].K = wK[i]; tw.w[idx].N = wN[i]; tw.w[idx].tbase = wTb[idx];
    }
  k_twt<<<1728, 256, 0, stream>>>(tw);

  const float* b0a = (const float*)d_in[5];  const float* b0b = (const float*)d_in[13];
  const float* b1a = (const float*)d_in[7];  const float* b1b = (const float*)d_in[15];
  const float* b2a = (const float*)d_in[9];  const float* b2b = (const float*)d_in[17];
  const float* boa = (const float*)d_in[11]; const float* bob = (const float*)d_in[19];

  k_gemm<1, 0><<<dim3(16, 16, 2), 256, 0, stream>>>(
      xh, xh + 786432, wt, wt + 3538944, b0a, b0b, h1, h1 + 1048576, 768, 1024);
  k_gemm<1, 0><<<dim3(16, 16, 2), 256, 0, stream>>>(
      h1, h1 + 1048576, wt + 786432, wt + 3538944 + 786432, b1a, b1b,
      h2, h2 + 1048576, 1024, 1024);
  k_gemm<1, 0><<<dim3(16, 16, 2), 256, 0, stream>>>(
      h2, h2 + 1048576, wt + 1835008, wt + 3538944 + 1835008, b2a, b2b,
      h1, h1 + 1048576, 1024, 1024);
  k_gemm<0, 1><<<dim3(10, 16, 2), 256, 0, stream>>>(
      h1, h1 + 1048576, wt + 2883584, wt + 3538944 + 2883584, boa, bob,
      qf, qf + 655360, 1024, 640);

  k_zscore<<<dim3(2560, 1, 2), 256, 0, stream>>>(qf, qh);
  k_aff<<<dim3(16, 16, 10), 256, 0, stream>>>(qh, aff, bmax);
  k_pass2<<<dim3(32, 32), 256, 0, stream>>>(aff, bmax, Aout, abf);

  // zero the 20 colsum slots (aff region is dead now)
  k_zero<<<200, 256, 0, stream>>>(slots);

  // 20 Sinkhorn iterations, one launch each, single A pass per iteration
  k_it<1><<<dim3(32, 10), 256, 0, stream>>>(abf, p1, p2, slots, slots, ub, 0);
  for (int it = 1; it < 20; ++it)
    k_it<0><<<dim3(32, 10), 256, 0, stream>>>(
        abf, p1, p2, slots + (it - 1) * 10240, slots + it * 10240, ub, it == 19);

  k_pwrite<<<dim3(32, 32), 256, 0, stream>>>(abf, slots + 19 * 10240, ub, p2, Pout);
}